// Round 6
// baseline (101.776 us; speedup 1.0000x reference)
//
#include <hip/hip_runtime.h>
#include <math.h>

#define BLOCK 256
#define NSPLIT 16      // nPerBlock = N/NSPLIT = 128 samples per block

#if __has_builtin(__builtin_amdgcn_exp2f)
#define EXP2F(x) __builtin_amdgcn_exp2f(x)
#else
#define EXP2F(x) exp2f(x)
#endif

// out[b,m] = coefN * sum_n exp2(a_n*px + b_n*py - (c_n + q_m))
//   a = 2t*sx, b = 2t*sy, c = t*|s|^2, q_m = t*|p_m|^2
// Sample constants are computed in-block and staged in LDS; the j-loop reads
// them with same-address ds_read_b128 (broadcast, conflict-free, LDS pipe)
// so neither the scalar cache nor the main VALU sits on the critical path.
// Bottleneck by design: the 4-lane transcendental pipe (16 cyc / wave64 exp).
__global__ __launch_bounds__(BLOCK, 8) void kde_kernel(
    const float* __restrict__ inputs,   // (B, N, 2)
    const float* __restrict__ points,   // (M, 2)
    float* __restrict__ out,            // (B, M), pre-zeroed
    int N, int M, int nPerBlock, float t, float t2, float coefN)
{
    const int b   = blockIdx.y;
    const int n0  = blockIdx.x * nPerBlock;
    const int tid = (int)threadIdx.x;

    __shared__ float4 S[128];           // a, b, c, pad  (2 KB)

    if (tid < nPerBlock) {
        float2 s = reinterpret_cast<const float2*>(inputs)[b * N + n0 + tid];
        S[tid] = make_float4(t2 * s.x, t2 * s.y,
                             t * fmaf(s.x, s.x, s.y * s.y), 0.f);
    }

    const int m0 = tid;
    const int m1 = tid + BLOCK;
    const float2* pts = reinterpret_cast<const float2*>(points);
    float2 p0 = pts[m0 < M ? m0 : 0];
    float2 p1 = pts[m1 < M ? m1 : 0];
    const float q0 = t * fmaf(p0.x, p0.x, p0.y * p0.y);
    const float q1 = t * fmaf(p1.x, p1.x, p1.y * p1.y);

    __syncthreads();

    float acc0 = 0.f, acc1 = 0.f;
#pragma unroll 16
    for (int j = 0; j < nPerBlock; ++j) {
        const float4 s = S[j];          // ds_read_b128, broadcast
        const float cq0 = s.z + q0;
        const float cq1 = s.z + q1;
        const float w0 = fmaf(s.x, p0.x, fmaf(s.y, p0.y, -cq0));
        const float w1 = fmaf(s.x, p1.x, fmaf(s.y, p1.y, -cq1));
        acc0 += EXP2F(w0);
        acc1 += EXP2F(w1);
    }

    if (m0 < M) atomicAdd(&out[(size_t)b * M + m0], acc0 * coefN);
    if (m1 < M) atomicAdd(&out[(size_t)b * M + m1], acc1 * coefN);
}

extern "C" void kernel_launch(void* const* d_in, const int* in_sizes, int n_in,
                              void* d_out, int out_size, void* d_ws, size_t ws_size,
                              hipStream_t stream) {
    const float* inputs = (const float*)d_in[0];   // (B, N, 2) fp32
    const float* points = (const float*)d_in[1];   // (M, 2) fp32
    float* out = (float*)d_out;                    // (B, M) fp32

    const int M = in_sizes[1] / 2;          // 512
    const int B = out_size / M;             // 128
    const int N = in_sizes[0] / (2 * B);    // 2048

    // Silverman bandwidth, d = 2
    const double h    = pow(4.0 / 4.0, 1.0 / 6.0) * pow((double)N, -1.0 / 6.0);
    const double h2   = h * h;
    const double coef = 1.0 / (2.0 * M_PI * h2);
    const double td   = 0.5 / (h2 * M_LN2);       // exp(-0.5*sq/h^2) = exp2(-t*sq)
    const float  t     = (float)td;
    const float  t2    = (float)(2.0 * td);
    const float  coefN = (float)(coef / (double)N);

    hipMemsetAsync(out, 0, (size_t)out_size * sizeof(float), stream);

    const int nPerBlock = N / NSPLIT;       // 128
    dim3 grid(NSPLIT, B);
    kde_kernel<<<grid, BLOCK, 0, stream>>>(inputs, points, out,
                                           N, M, nPerBlock, t, t2, coefN);
}

// Round 7
// 75.552 us; speedup vs baseline: 1.3471x; 1.3471x over previous
//
#include <hip/hip_runtime.h>
#include <math.h>

#define BLOCK 256
#define NSPLIT 32      // nPerBlock = N/NSPLIT = 64 samples per block
#define CHUNK 8

#if __has_builtin(__builtin_amdgcn_exp2f)
#define EXP2F(x) __builtin_amdgcn_exp2f(x)
#else
#define EXP2F(x) exp2f(x)
#endif

// out[b,m] = coefN * sum_n exp2(a_n*px + b_n*py - (c_n + q_m))
//   a = 2t*sx, b = 2t*sy, c = t*|s|^2, q_m = t*|p_m|^2
// Samples staged in LDS (computed in-block), then consumed through an
// explicit CHUNK=8 register double-buffer: 8 ds_read_b128 in flight while
// the previous 8 samples' 16 exps (512 trans-cyc) execute. VGPR cap 128
// (launch_bounds 256,4) so the buffers actually live in registers --
// R6's 32-VGPR allocation serialized every ds_read (VALUBusy 34%).
// Design bottleneck: trans pipe, 16 cyc / wave64 v_exp_f32 -> 13.7 us floor.
__global__ __launch_bounds__(BLOCK, 4) void kde_kernel(
    const float* __restrict__ inputs,   // (B, N, 2)
    const float* __restrict__ points,   // (M, 2)
    float* __restrict__ out,            // (B, M), pre-zeroed
    int N, int M, int nPerBlock, float t, float t2, float coefN)
{
    const int b   = blockIdx.y;
    const int n0  = blockIdx.x * nPerBlock;
    const int tid = (int)threadIdx.x;

    __shared__ float4 S[64];            // a, b, c, pad  (1 KB)

    if (tid < nPerBlock) {
        float2 s = reinterpret_cast<const float2*>(inputs)[b * N + n0 + tid];
        S[tid] = make_float4(t2 * s.x, t2 * s.y,
                             t * fmaf(s.x, s.x, s.y * s.y), 0.f);
    }

    const int m0 = tid;
    const int m1 = tid + BLOCK;
    const float2* pts = reinterpret_cast<const float2*>(points);
    float2 p0 = pts[m0 < M ? m0 : 0];
    float2 p1 = pts[m1 < M ? m1 : 0];
    const float q0 = t * fmaf(p0.x, p0.x, p0.y * p0.y);
    const float q1 = t * fmaf(p1.x, p1.x, p1.y * p1.y);

    __syncthreads();

    float acc0 = 0.f, acc1 = 0.f;

    float4 cur[CHUNK], nxt[CHUNK];
#pragma unroll
    for (int j = 0; j < CHUNK; ++j) cur[j] = S[j];

    for (int i0 = 0; i0 < nPerBlock; i0 += CHUNK) {
        const int inext = (i0 + CHUNK < nPerBlock) ? i0 + CHUNK : 0; // wrap: harmless re-read
#pragma unroll
        for (int j = 0; j < CHUNK; ++j) nxt[j] = S[inext + j];

#pragma unroll
        for (int j = 0; j < CHUNK; ++j) {
            const float4 s = cur[j];
            const float w0 = fmaf(s.x, p0.x, fmaf(s.y, p0.y, -(s.z + q0)));
            const float w1 = fmaf(s.x, p1.x, fmaf(s.y, p1.y, -(s.z + q1)));
            acc0 += EXP2F(w0);
            acc1 += EXP2F(w1);
        }
#pragma unroll
        for (int j = 0; j < CHUNK; ++j) cur[j] = nxt[j];
    }

    if (m0 < M) atomicAdd(&out[(size_t)b * M + m0], acc0 * coefN);
    if (m1 < M) atomicAdd(&out[(size_t)b * M + m1], acc1 * coefN);
}

extern "C" void kernel_launch(void* const* d_in, const int* in_sizes, int n_in,
                              void* d_out, int out_size, void* d_ws, size_t ws_size,
                              hipStream_t stream) {
    const float* inputs = (const float*)d_in[0];   // (B, N, 2) fp32
    const float* points = (const float*)d_in[1];   // (M, 2) fp32
    float* out = (float*)d_out;                    // (B, M) fp32

    const int M = in_sizes[1] / 2;          // 512
    const int B = out_size / M;             // 128
    const int N = in_sizes[0] / (2 * B);    // 2048

    // Silverman bandwidth, d = 2
    const double h    = pow(4.0 / 4.0, 1.0 / 6.0) * pow((double)N, -1.0 / 6.0);
    const double h2   = h * h;
    const double coef = 1.0 / (2.0 * M_PI * h2);
    const double td   = 0.5 / (h2 * M_LN2);       // exp(-0.5*sq/h^2) = exp2(-t*sq)
    const float  t     = (float)td;
    const float  t2    = (float)(2.0 * td);
    const float  coefN = (float)(coef / (double)N);

    hipMemsetAsync(out, 0, (size_t)out_size * sizeof(float), stream);

    const int nPerBlock = N / NSPLIT;       // 64
    dim3 grid(NSPLIT, B);
    kde_kernel<<<grid, BLOCK, 0, stream>>>(inputs, points, out,
                                           N, M, nPerBlock, t, t2, coefN);
}

// Round 9
// 74.351 us; speedup vs baseline: 1.3688x; 1.0161x over previous
//
#include <hip/hip_runtime.h>
#include <math.h>

#define BLOCK 128
#define MPT 4          // m-points per thread (BLOCK * MPT = M = 512)

#if __has_builtin(__builtin_amdgcn_exp2f)
#define EXP2F(x) __builtin_amdgcn_exp2f(x)
#else
#define EXP2F(x) exp2f(x)
#endif

typedef float v2f __attribute__((ext_vector_type(2)));

// out[b,m] = coefN * sum_n exp2(a_n*px + b_n*py - c_n - q_m)
//   a = 2t*sx, b = 2t*sy, c = t*|s|^2, q_m = t*|p_m|^2  (argument always <= 0)
//
// HW model (fit to R1/R6/R7 counters within 3%): per-SIMD issue serializes;
// wave64 v_exp_f32 = 16 issue-cyc, VALU op = 2 cyc. Floor = pure exp issue
// = 13.7 us. This version packs math across SAMPLE pairs in native v2f
// __shared__ arrays (R8's reinterpret_cast<float*->v2f*> was TBAA-UB and
// produced post-timing divergence -- never alias LDS across types) and
// amortizes the 3 ds_read_b64 per sample-pair over MPT=4 m-points:
// per (pair, m): 4 pk ops (8 cyc) + 2 exp (32 cyc) + ~5 cyc ds share.
__global__ __launch_bounds__(BLOCK, 4) void kde_kernel(
    const float* __restrict__ inputs,   // (B, N, 2)
    const float* __restrict__ points,   // (M, 2)
    float* __restrict__ out,            // (B, M), pre-zeroed
    int N, int M, int nPairs, float t, float t2, float coefN)
{
    const int b   = blockIdx.y;
    const int n0  = blockIdx.x * (nPairs << 1);
    const int tid = (int)threadIdx.x;

    __shared__ v2f SA[32], SB[32], SC[32];   // packed sample pairs, 768 B

    if (tid < nPairs) {
        // two consecutive samples: (sx0, sy0, sx1, sy1)
        const float4 s2 =
            reinterpret_cast<const float4*>(inputs)[((b * N + n0) >> 1) + tid];
        SA[tid] = (v2f){t2 * s2.x, t2 * s2.z};
        SB[tid] = (v2f){t2 * s2.y, t2 * s2.w};
        SC[tid] = (v2f){t * fmaf(s2.x, s2.x, s2.y * s2.y),
                        t * fmaf(s2.z, s2.z, s2.w * s2.w)};
    }

    const float2* pts = reinterpret_cast<const float2*>(points);
    float px[MPT], py[MPT];
    v2f NQ[MPT];
#pragma unroll
    for (int k = 0; k < MPT; ++k) {
        const int m = tid + k * BLOCK;
        const float2 p = pts[m < M ? m : 0];
        px[k] = p.x;
        py[k] = p.y;
        const float q = t * fmaf(p.x, p.x, p.y * p.y);
        NQ[k] = (v2f){-q, -q};
    }

    __syncthreads();

    v2f acc[MPT];
#pragma unroll
    for (int k = 0; k < MPT; ++k) acc[k] = (v2f){0.f, 0.f};

#pragma unroll 8
    for (int j = 0; j < nPairs; ++j) {
        const v2f a  = SA[j];           // ds_read_b64 -> register pair
        const v2f bb = SB[j];
        const v2f c  = SC[j];
#pragma unroll
        for (int k = 0; k < MPT; ++k) {
            const v2f w = __builtin_elementwise_fma(a, (v2f){px[k], px[k]},
                              __builtin_elementwise_fma(bb, (v2f){py[k], py[k]},
                                                        NQ[k] - c));
            v2f e;
            e.x = EXP2F(w.x);
            e.y = EXP2F(w.y);
            acc[k] += e;                // v_pk_add_f32
        }
    }

#pragma unroll
    for (int k = 0; k < MPT; ++k) {
        const int m = tid + k * BLOCK;
        if (m < M)
            atomicAdd(&out[(size_t)b * M + m], (acc[k].x + acc[k].y) * coefN);
    }
}

extern "C" void kernel_launch(void* const* d_in, const int* in_sizes, int n_in,
                              void* d_out, int out_size, void* d_ws, size_t ws_size,
                              hipStream_t stream) {
    const float* inputs = (const float*)d_in[0];   // (B, N, 2) fp32
    const float* points = (const float*)d_in[1];   // (M, 2) fp32
    float* out = (float*)d_out;                    // (B, M) fp32

    const int M = in_sizes[1] / 2;          // 512
    const int B = out_size / M;             // 128
    const int N = in_sizes[0] / (2 * B);    // 2048

    // Silverman bandwidth, d = 2
    const double h    = pow(4.0 / 4.0, 1.0 / 6.0) * pow((double)N, -1.0 / 6.0);
    const double h2   = h * h;
    const double coef = 1.0 / (2.0 * M_PI * h2);
    const double td   = 0.5 / (h2 * M_LN2);       // exp(-0.5*sq/h^2) = exp2(-t*sq)
    const float  t     = (float)td;
    const float  t2    = (float)(2.0 * td);
    const float  coefN = (float)(coef / (double)N);

    hipMemsetAsync(out, 0, (size_t)out_size * sizeof(float), stream);

    const int nPerBlock = 64;               // matches __shared__ capacity (32 pairs)
    const int nsplit = N / nPerBlock;       // 32
    dim3 grid(nsplit, B);
    kde_kernel<<<grid, BLOCK, 0, stream>>>(inputs, points, out,
                                           N, M, nPerBlock >> 1, t, t2, coefN);
}